// Round 1
// baseline (592.968 us; speedup 1.0000x reference)
//
#include <hip/hip_runtime.h>

// Problem dims (fixed by harness)
#define NN 512
#define LL 1024
#define SS 3
#define DD 128
#define KK 4
#define HH 32
#define GG 64
#define NL (NN * LL)

// tanh-form GELU: max |err| vs exact erf-GELU ~3e-4, amplified <~0.01 through
// w2 sums -- far under the 4.19e-2 absmax threshold. ~10 VALU ops (1 v_exp).
__device__ __forceinline__ float fast_gelu(float x) {
    const float c0 = 0.7978845608028654f;
    const float c1 = 0.7978845608028654f * 0.044715f;
    float u = x * x;
    float y = x * fmaf(c1, u, c0);        // inner of tanh
    float e = __expf(2.0f * y);           // overflow-safe: inf -> t=1, 0 -> t=-1
    float r = __builtin_amdgcn_rcpf(e + 1.0f);
    float t = fmaf(-2.0f, r, 1.0f);       // tanh(y)
    return 0.5f * x * (1.0f + t);
}

// Kernel 1: per-n graph_ctx mean over L (256 MiB read) + situation MLP.
// One block per n. 256 threads: col-group c = t&31 (float4), row-stream rs = t>>5.
__global__ __launch_bounds__(256) void k_sit(
    const float* __restrict__ veh, const float* __restrict__ cust,
    const float* __restrict__ w1, const float* __restrict__ b1,
    const float* __restrict__ w2, const float* __restrict__ b2,
    float* __restrict__ sit_out)
{
    __shared__ float4 red[256];
    __shared__ float sin_[2 * DD];
    __shared__ float hg[GG];
    const int n = blockIdx.x;
    const int t = threadIdx.x;
    const int c = t & 31, rs = t >> 5;
    const float4* cp = (const float4*)(cust + (size_t)n * LL * DD);

    // 4 independent accumulators -> 4 loads in flight per thread
    float4 a0 = make_float4(0.f, 0.f, 0.f, 0.f), a1 = a0, a2 = a0, a3 = a0;
    for (int l = rs; l < LL; l += 32) {
        float4 v0 = cp[(l     ) * 32 + c];
        float4 v1 = cp[(l +  8) * 32 + c];
        float4 v2 = cp[(l + 16) * 32 + c];
        float4 v3 = cp[(l + 24) * 32 + c];
        a0.x += v0.x; a0.y += v0.y; a0.z += v0.z; a0.w += v0.w;
        a1.x += v1.x; a1.y += v1.y; a1.z += v1.z; a1.w += v1.w;
        a2.x += v2.x; a2.y += v2.y; a2.z += v2.z; a2.w += v2.w;
        a3.x += v3.x; a3.y += v3.y; a3.z += v3.z; a3.w += v3.w;
    }
    a0.x += a1.x + a2.x + a3.x;
    a0.y += a1.y + a2.y + a3.y;
    a0.z += a1.z + a2.z + a3.z;
    a0.w += a1.w + a2.w + a3.w;
    red[t] = a0;
    __syncthreads();

    if (t < 32) {
        float4 s = red[t];
        #pragma unroll
        for (int i = 1; i < 8; i++) {
            float4 v = red[i * 32 + t];
            s.x += v.x; s.y += v.y; s.z += v.z; s.w += v.w;
        }
        const float inv = 1.0f / (float)LL;
        sin_[DD + 4 * t + 0] = s.x * inv;
        sin_[DD + 4 * t + 1] = s.y * inv;
        sin_[DD + 4 * t + 2] = s.z * inv;
        sin_[DD + 4 * t + 3] = s.w * inv;
        float4 vv = ((const float4*)(veh + (size_t)n * DD))[t];
        sin_[4 * t + 0] = vv.x; sin_[4 * t + 1] = vv.y;
        sin_[4 * t + 2] = vv.z; sin_[4 * t + 3] = vv.w;
    }
    __syncthreads();

    if (t < GG) {
        float a = b1[t];
        #pragma unroll 8
        for (int i = 0; i < 2 * DD; i++)
            a = fmaf(sin_[i], w1[i * GG + t], a);
        hg[t] = fast_gelu(a);
    }
    __syncthreads();

    if (t < KK) {
        float a = b2[t];
        #pragma unroll
        for (int g = 0; g < GG; g++)
            a = fmaf(hg[g], w2[g * KK + t], a);
        sit_out[n * KK + t] = a;
    }
}

// Kernel 2: fused cand logits + gate softmax + expert MLP + combine.
// 32 lanes per element, 2 elements per wave. Lane r (=lane&31):
//   - owns edge dims d in [4r, 4r+4) (one float4, coalesced 1 KiB/wave)
//   - owns expert/gate channel k = r&3, hidden quad j in [(r>>2)*4, +4)
__global__ __launch_bounds__(256) void k_fuse(
    const float* __restrict__ scores, const float* __restrict__ edge,
    const float* __restrict__ sit,
    const float* __restrict__ ew1, const float* __restrict__ eb1,
    const float* __restrict__ ew2, const float* __restrict__ eb2,
    const float* __restrict__ cand_w, const float* __restrict__ cand_b,
    const float* __restrict__ edge_w, const float* __restrict__ gbp,
    float* __restrict__ out)
{
    const int lane = threadIdx.x & 63;
    const int r = lane & 31;
    const int wave = (blockIdx.x * blockDim.x + threadIdx.x) >> 6;
    const int gi0 = wave * 2 + (lane >> 5);
    const int stride = ((gridDim.x * blockDim.x) >> 6) * 2;

    const int ko = r & 3;        // owned gate/expert channel
    const int jg = r >> 2;       // owned hidden quad (0..7)
    const bool kb0 = (r & 1) != 0;
    const bool kb1 = (r & 2) != 0;

    // Preload per-lane constant weights into VGPRs
    const float4* ew4 = (const float4*)edge_w;            // (D,K): row d = 1 float4
    const float4 wqa = ew4[4 * r + 0];
    const float4 wqb = ew4[4 * r + 1];
    const float4 wqc = ew4[4 * r + 2];
    const float4 wqd = ew4[4 * r + 3];
    const float cw0 = cand_w[0 * KK + ko];
    const float cw1 = cand_w[1 * KK + ko];
    const float cw2 = cand_w[2 * KK + ko];
    const float cb  = cand_b[ko];
    const float4* w1f = (const float4*)ew1;               // (K,S,H)
    const float4 w1a = w1f[(ko * SS + 0) * (HH / 4) + jg];
    const float4 w1b = w1f[(ko * SS + 1) * (HH / 4) + jg];
    const float4 w1c = w1f[(ko * SS + 2) * (HH / 4) + jg];
    const float4 b1v = ((const float4*)eb1)[ko * (HH / 4) + jg];
    const float4 w2v = ((const float4*)ew2)[ko * (HH / 4) + jg];
    const float b2o = eb2[ko];
    const float gbv = gbp[0];
    const float alpha = 1.0f / (1.0f + __expf(-gbv));
    const float onema = 1.0f - alpha;

    for (int e = gi0; e < NL; e += stride) {
        // ---- edge dot: partials for all 4 k over 4 owned d's
        const float4 ev = *(const float4*)(edge + (size_t)e * DD + r * 4);
        float p0 = ev.x * wqa.x; p0 = fmaf(ev.y, wqb.x, p0); p0 = fmaf(ev.z, wqc.x, p0); p0 = fmaf(ev.w, wqd.x, p0);
        float p1 = ev.x * wqa.y; p1 = fmaf(ev.y, wqb.y, p1); p1 = fmaf(ev.z, wqc.y, p1); p1 = fmaf(ev.w, wqd.y, p1);
        float p2 = ev.x * wqa.z; p2 = fmaf(ev.y, wqb.z, p2); p2 = fmaf(ev.z, wqc.z, p2); p2 = fmaf(ev.w, wqd.z, p2);
        float p3 = ev.x * wqa.w; p3 = fmaf(ev.y, wqb.w, p3); p3 = fmaf(ev.z, wqc.w, p3); p3 = fmaf(ev.w, wqd.w, p3);
        // reduce within 4-lane groups, transpose-select own k, reduce across groups
        p0 += __shfl_xor(p0, 1); p1 += __shfl_xor(p1, 1); p2 += __shfl_xor(p2, 1); p3 += __shfl_xor(p3, 1);
        p0 += __shfl_xor(p0, 2); p1 += __shfl_xor(p1, 2); p2 += __shfl_xor(p2, 2); p3 += __shfl_xor(p3, 2);
        float qa = kb0 ? p1 : p0;
        float qb = kb0 ? p3 : p2;
        float q  = kb1 ? qb : qa;
        q += __shfl_xor(q, 4); q += __shfl_xor(q, 8); q += __shfl_xor(q, 16);
        // q = edge_dot[k=ko] (replicated across the 8 lanes sharing ko)

        // ---- scores (wave-uniform per element -> broadcast loads)
        const float s0 = scores[(size_t)e * 3 + 0];
        const float s1 = scores[(size_t)e * 3 + 1];
        const float s2 = scores[(size_t)e * 3 + 2];

        // ---- candidate logit for own k
        float cand = fmaf(s0, cw0, fmaf(s1, cw1, fmaf(s2, cw2, cb))) + q;

        // ---- situation logit for own k
        const float4 sl = *(const float4*)(sit + (e >> 10) * 4);
        float sa = kb0 ? sl.y : sl.x;
        float sb = kb0 ? sl.w : sl.z;
        float so = kb1 ? sb : sa;
        float gl = fmaf(alpha, so, onema * cand);

        // ---- softmax over k (xor{1,2} groups hold k=0..3)
        float m = gl;
        m = fmaxf(m, __shfl_xor(m, 1));
        m = fmaxf(m, __shfl_xor(m, 2));
        float ex = __expf(gl - m);
        float se = ex;
        se += __shfl_xor(se, 1);
        se += __shfl_xor(se, 2);
        float gw = ex * __builtin_amdgcn_rcpf(se);

        // ---- expert MLP: 4 hidden units for own k
        float acc;
        {
            float z, h;
            z = fmaf(s0, w1a.x, fmaf(s1, w1b.x, fmaf(s2, w1c.x, b1v.x))); h = fast_gelu(z); acc = h * w2v.x;
            z = fmaf(s0, w1a.y, fmaf(s1, w1b.y, fmaf(s2, w1c.y, b1v.y))); h = fast_gelu(z); acc = fmaf(h, w2v.y, acc);
            z = fmaf(s0, w1a.z, fmaf(s1, w1b.z, fmaf(s2, w1c.z, b1v.z))); h = fast_gelu(z); acc = fmaf(h, w2v.z, acc);
            z = fmaf(s0, w1a.w, fmaf(s1, w1b.w, fmaf(s2, w1c.w, b1v.w))); h = fast_gelu(z); acc = fmaf(h, w2v.w, acc);
        }
        acc += __shfl_xor(acc, 4); acc += __shfl_xor(acc, 8); acc += __shfl_xor(acc, 16);
        // acc = expert_out[k=ko] (minus bias)

        // ---- combine: t_k = gate_w[k] * expert_out[k]; sum over k
        float tk = gw * (acc + b2o);
        tk += __shfl_xor(tk, 1);
        tk += __shfl_xor(tk, 2);
        if (r == 0) out[e] = tk;
    }
}

extern "C" void kernel_launch(void* const* d_in, const int* in_sizes, int n_in,
                              void* d_out, int out_size, void* d_ws, size_t ws_size,
                              hipStream_t stream)
{
    const float* scores = (const float*)d_in[0];
    const float* veh    = (const float*)d_in[1];
    const float* cust   = (const float*)d_in[2];
    const float* edge   = (const float*)d_in[3];
    const float* ew1    = (const float*)d_in[4];
    const float* eb1    = (const float*)d_in[5];
    const float* ew2    = (const float*)d_in[6];
    const float* eb2    = (const float*)d_in[7];
    const float* sw1    = (const float*)d_in[8];
    const float* sb1    = (const float*)d_in[9];
    const float* sw2    = (const float*)d_in[10];
    const float* sb2    = (const float*)d_in[11];
    const float* cw     = (const float*)d_in[12];
    const float* cb     = (const float*)d_in[13];
    const float* egw    = (const float*)d_in[14];
    const float* gb     = (const float*)d_in[15];
    float* out = (float*)d_out;
    float* sit = (float*)d_ws;   // N*K floats = 8 KB of scratch

    hipLaunchKernelGGL(k_sit, dim3(NN), dim3(256), 0, stream,
                       veh, cust, sw1, sb1, sw2, sb2, sit);
    hipLaunchKernelGGL(k_fuse, dim3(2048), dim3(256), 0, stream,
                       scores, edge, sit, ew1, eb1, ew2, eb2, cw, cb, egw, gb, out);
}

// Round 2
// 577.701 us; speedup vs baseline: 1.0264x; 1.0264x over previous
//
#include <hip/hip_runtime.h>

// Problem dims (fixed by harness)
#define NN 512
#define LL 1024
#define SS 3
#define DD 128
#define KK 4
#define HH 32
#define GG 64

// tanh-form GELU: max |err| vs exact erf-GELU ~3e-4, amplified <~0.01 through
// w2 sums -- far under the 4.19e-2 absmax threshold. ~10 VALU ops (1 v_exp).
__device__ __forceinline__ float fast_gelu(float x) {
    const float c0 = 0.7978845608028654f;
    const float c1 = 0.7978845608028654f * 0.044715f;
    float u = x * x;
    float y = x * fmaf(c1, u, c0);        // inner of tanh
    float e = __expf(2.0f * y);           // overflow-safe: inf -> t=1, 0 -> t=-1
    float r = __builtin_amdgcn_rcpf(e + 1.0f);
    float t = fmaf(-2.0f, r, 1.0f);       // tanh(y)
    return 0.5f * x * (1.0f + t);
}

// One block per n (512 blocks x 512 threads, all co-resident: 2 blocks/CU).
// Phase A: mean over L of cust_repr[n] (512 KiB coalesced stream).
// Phase B: situation MLP (256->64->4) in LDS; sit logits hoisted per-block.
// Phase C: 1024 elements, 32 lanes/element, 2 elements/wave:
//   lane r owns edge dims [4r,4r+4) (float4; wave reads 1 KiB contiguous),
//   owns gate/expert channel k=r&3 and hidden quad j=(r>>2)*4.
__global__ __launch_bounds__(512, 4) void k_all(
    const float* __restrict__ scores, const float* __restrict__ veh,
    const float* __restrict__ cust, const float* __restrict__ edge,
    const float* __restrict__ ew1, const float* __restrict__ eb1,
    const float* __restrict__ ew2, const float* __restrict__ eb2,
    const float* __restrict__ sw1, const float* __restrict__ sb1,
    const float* __restrict__ sw2, const float* __restrict__ sb2,
    const float* __restrict__ cand_w, const float* __restrict__ cand_b,
    const float* __restrict__ edge_w, const float* __restrict__ gbp,
    float* __restrict__ out)
{
    __shared__ float4 red[512];
    __shared__ float sin_[2 * DD];
    __shared__ float hg[GG];
    __shared__ float slds[KK];

    const int n = blockIdx.x;
    const int t = threadIdx.x;
    const int lane = t & 63;
    const int r = lane & 31;

    // ---- per-lane phase-C weight preloads, issued early so latency hides
    // behind phase A's streaming loads
    const int ko = r & 3;        // owned gate/expert channel
    const int jg = r >> 2;       // owned hidden quad (0..7)
    const bool kb0 = (r & 1) != 0;
    const bool kb1 = (r & 2) != 0;
    const float4* ew4 = (const float4*)edge_w;            // (D,K): row d = 1 float4
    const float4 wqa = ew4[4 * r + 0];
    const float4 wqb = ew4[4 * r + 1];
    const float4 wqc = ew4[4 * r + 2];
    const float4 wqd = ew4[4 * r + 3];
    const float cw0 = cand_w[0 * KK + ko];
    const float cw1 = cand_w[1 * KK + ko];
    const float cw2 = cand_w[2 * KK + ko];
    const float cb  = cand_b[ko];
    const float4* w1f = (const float4*)ew1;               // (K,S,H)
    const float4 w1a = w1f[(ko * SS + 0) * (HH / 4) + jg];
    const float4 w1b = w1f[(ko * SS + 1) * (HH / 4) + jg];
    const float4 w1c = w1f[(ko * SS + 2) * (HH / 4) + jg];
    const float4 b1v = ((const float4*)eb1)[ko * (HH / 4) + jg];
    const float4 w2v = ((const float4*)ew2)[ko * (HH / 4) + jg];
    const float b2o = eb2[ko];
    const float gbv = gbp[0];
    const float alpha = 1.0f / (1.0f + __expf(-gbv));
    const float onema = 1.0f - alpha;

    // ---- Phase A: mean over L (rows) of cust[n] ----
    const int c = t & 31;        // float4 column group
    const int rs = t >> 5;       // row stream 0..15
    const float4* cp = (const float4*)(cust + (size_t)n * LL * DD);
    float4 a0 = make_float4(0.f, 0.f, 0.f, 0.f), a1 = a0, a2 = a0, a3 = a0;
    #pragma unroll 4
    for (int i = 0; i < 16; ++i) {
        // rows rs+16i (+0,+256,+512,+768): lanes 0-31 row X, 32-63 row X+1
        float4 v0 = cp[(rs + 16 * i      ) * 32 + c];
        float4 v1 = cp[(rs + 16 * i + 256) * 32 + c];
        float4 v2 = cp[(rs + 16 * i + 512) * 32 + c];
        float4 v3 = cp[(rs + 16 * i + 768) * 32 + c];
        a0.x += v0.x; a0.y += v0.y; a0.z += v0.z; a0.w += v0.w;
        a1.x += v1.x; a1.y += v1.y; a1.z += v1.z; a1.w += v1.w;
        a2.x += v2.x; a2.y += v2.y; a2.z += v2.z; a2.w += v2.w;
        a3.x += v3.x; a3.y += v3.y; a3.z += v3.z; a3.w += v3.w;
    }
    a0.x += a1.x + a2.x + a3.x;
    a0.y += a1.y + a2.y + a3.y;
    a0.z += a1.z + a2.z + a3.z;
    a0.w += a1.w + a2.w + a3.w;
    red[t] = a0;
    __syncthreads();

    if (t < 32) {
        float4 s = red[t];
        #pragma unroll
        for (int i = 1; i < 16; i++) {
            float4 v = red[i * 32 + t];
            s.x += v.x; s.y += v.y; s.z += v.z; s.w += v.w;
        }
        const float inv = 1.0f / (float)LL;
        sin_[DD + 4 * t + 0] = s.x * inv;
        sin_[DD + 4 * t + 1] = s.y * inv;
        sin_[DD + 4 * t + 2] = s.z * inv;
        sin_[DD + 4 * t + 3] = s.w * inv;
        float4 vv = ((const float4*)(veh + (size_t)n * DD))[t];
        sin_[4 * t + 0] = vv.x; sin_[4 * t + 1] = vv.y;
        sin_[4 * t + 2] = vv.z; sin_[4 * t + 3] = vv.w;
    }
    __syncthreads();

    // ---- Phase B: situation MLP ----
    if (t < GG) {
        float a = sb1[t];
        #pragma unroll 8
        for (int i = 0; i < 2 * DD; i++)
            a = fmaf(sin_[i], sw1[i * GG + t], a);
        hg[t] = fast_gelu(a);
    }
    __syncthreads();
    if (t < KK) {
        float a = sb2[t];
        #pragma unroll
        for (int g = 0; g < GG; g++)
            a = fmaf(hg[g], sw2[g * KK + t], a);
        slds[t] = a;
    }
    __syncthreads();

    // Hoist per-n situation logit select + alpha-blend out of the loop:
    // gl = alpha*sit[k] + onema*(cand) ; cand = s.cw + cb + q
    //    = sbase + onema*(s.cw + q)
    const float sl0 = slds[0], sl1 = slds[1], sl2 = slds[2], sl3 = slds[3];
    float sa_ = kb0 ? sl1 : sl0;
    float sb_ = kb0 ? sl3 : sl2;
    float so  = kb1 ? sb_ : sa_;
    const float sbase = fmaf(alpha, so, onema * cb);

    // ---- Phase C: 1024 elements of this n ----
    const int w = t >> 6;                 // wave 0..7
    const int half = lane >> 5;           // element within wave
    const float* sc_base = scores + (size_t)n * LL * SS;
    const float* ed_base = edge + (size_t)n * LL * DD;
    float* out_base = out + (size_t)n * LL;

    for (int i = 0; i < 64; ++i) {
        const int el = w * 2 + half + i * 16;   // 0..1023
        // edge dot: partials for all 4 k over 4 owned dims
        const float4 ev = *(const float4*)(ed_base + (size_t)el * DD + r * 4);
        float p0 = ev.x * wqa.x; p0 = fmaf(ev.y, wqb.x, p0); p0 = fmaf(ev.z, wqc.x, p0); p0 = fmaf(ev.w, wqd.x, p0);
        float p1 = ev.x * wqa.y; p1 = fmaf(ev.y, wqb.y, p1); p1 = fmaf(ev.z, wqc.y, p1); p1 = fmaf(ev.w, wqd.y, p1);
        float p2 = ev.x * wqa.z; p2 = fmaf(ev.y, wqb.z, p2); p2 = fmaf(ev.z, wqc.z, p2); p2 = fmaf(ev.w, wqd.z, p2);
        float p3 = ev.x * wqa.w; p3 = fmaf(ev.y, wqb.w, p3); p3 = fmaf(ev.z, wqc.w, p3); p3 = fmaf(ev.w, wqd.w, p3);
        // reduce within 4-lane groups, transpose-select own k, reduce across groups
        p0 += __shfl_xor(p0, 1); p1 += __shfl_xor(p1, 1); p2 += __shfl_xor(p2, 1); p3 += __shfl_xor(p3, 1);
        p0 += __shfl_xor(p0, 2); p1 += __shfl_xor(p1, 2); p2 += __shfl_xor(p2, 2); p3 += __shfl_xor(p3, 2);
        float qa = kb0 ? p1 : p0;
        float qb = kb0 ? p3 : p2;
        float q  = kb1 ? qb : qa;
        q += __shfl_xor(q, 4); q += __shfl_xor(q, 8); q += __shfl_xor(q, 16);
        // q = edge_dot[k=ko] (replicated across the 8 lanes sharing ko)

        // scores (uniform per half-wave -> broadcast loads)
        const float s0 = sc_base[el * 3 + 0];
        const float s1 = sc_base[el * 3 + 1];
        const float s2 = sc_base[el * 3 + 2];

        // gate logit for own k
        const float sdot = fmaf(s0, cw0, fmaf(s1, cw1, s2 * cw2));
        const float gl = fmaf(onema, sdot + q, sbase);

        // softmax over k (xor{1,2} groups hold k=0..3)
        float m = gl;
        m = fmaxf(m, __shfl_xor(m, 1));
        m = fmaxf(m, __shfl_xor(m, 2));
        float ex = __expf(gl - m);
        float se = ex;
        se += __shfl_xor(se, 1);
        se += __shfl_xor(se, 2);
        float gw = ex * __builtin_amdgcn_rcpf(se);

        // expert MLP: 4 hidden units for own k
        float acc;
        {
            float z, h;
            z = fmaf(s0, w1a.x, fmaf(s1, w1b.x, fmaf(s2, w1c.x, b1v.x))); h = fast_gelu(z); acc = h * w2v.x;
            z = fmaf(s0, w1a.y, fmaf(s1, w1b.y, fmaf(s2, w1c.y, b1v.y))); h = fast_gelu(z); acc = fmaf(h, w2v.y, acc);
            z = fmaf(s0, w1a.z, fmaf(s1, w1b.z, fmaf(s2, w1c.z, b1v.z))); h = fast_gelu(z); acc = fmaf(h, w2v.z, acc);
            z = fmaf(s0, w1a.w, fmaf(s1, w1b.w, fmaf(s2, w1c.w, b1v.w))); h = fast_gelu(z); acc = fmaf(h, w2v.w, acc);
        }
        acc += __shfl_xor(acc, 4); acc += __shfl_xor(acc, 8); acc += __shfl_xor(acc, 16);

        // combine: sum_k gate_w[k]*expert_out[k]
        float tk = gw * (acc + b2o);
        tk += __shfl_xor(tk, 1);
        tk += __shfl_xor(tk, 2);
        if (r == 0) out_base[el] = tk;
    }
}

extern "C" void kernel_launch(void* const* d_in, const int* in_sizes, int n_in,
                              void* d_out, int out_size, void* d_ws, size_t ws_size,
                              hipStream_t stream)
{
    const float* scores = (const float*)d_in[0];
    const float* veh    = (const float*)d_in[1];
    const float* cust   = (const float*)d_in[2];
    const float* edge   = (const float*)d_in[3];
    const float* ew1    = (const float*)d_in[4];
    const float* eb1    = (const float*)d_in[5];
    const float* ew2    = (const float*)d_in[6];
    const float* eb2    = (const float*)d_in[7];
    const float* sw1    = (const float*)d_in[8];
    const float* sb1    = (const float*)d_in[9];
    const float* sw2    = (const float*)d_in[10];
    const float* sb2    = (const float*)d_in[11];
    const float* cw     = (const float*)d_in[12];
    const float* cb     = (const float*)d_in[13];
    const float* egw    = (const float*)d_in[14];
    const float* gb     = (const float*)d_in[15];
    float* out = (float*)d_out;

    hipLaunchKernelGGL(k_all, dim3(NN), dim3(512), 0, stream,
                       scores, veh, cust, edge, ew1, eb1, ew2, eb2,
                       sw1, sb1, sw2, sb2, cw, cb, egw, gb, out);
}

// Round 3
// 559.429 us; speedup vs baseline: 1.0600x; 1.0327x over previous
//
#include <hip/hip_runtime.h>

// Problem dims (fixed by harness)
#define NN 512
#define LL 1024
#define SS 3
#define DD 128
#define KK 4
#define HH 32
#define GG 64

// ds_swizzle XOR patterns (BitMode: offset = (xor<<10) | (or<<5) | and, and=0x1F)
// Operates within 32-lane groups == our per-element lane group. Zero VALU setup.
#define SWZ1  0x041F
#define SWZ2  0x081F
#define SWZ4  0x101F
#define SWZ8  0x201F
#define SWZ16 0x401F
template <int IMM>
__device__ __forceinline__ float swz(float x) {
    return __int_as_float(__builtin_amdgcn_ds_swizzle(__float_as_int(x), IMM));
}

// tanh-form GELU: max |err| vs exact erf-GELU ~3e-4 -- far under threshold.
__device__ __forceinline__ float fast_gelu(float x) {
    const float c0 = 0.7978845608028654f;
    const float c1 = 0.7978845608028654f * 0.044715f;
    float u = x * x;
    float y = x * fmaf(c1, u, c0);
    float e = __expf(2.0f * y);
    float r = __builtin_amdgcn_rcpf(e + 1.0f);
    float t = fmaf(-2.0f, r, 1.0f);
    return 0.5f * x * (1.0f + t);
}

// One block per n (512 blocks x 512 threads, 2 blocks/CU, 16 waves/CU).
// Phase A: mean over L of cust_repr[n]. Phase B: situation MLP in LDS.
// Phase C: 32 lanes/element, 2 el/wave, 4 independent element-chains in
// flight (SoA unroll) so the DS-swizzle pipe runs at throughput not latency.
__global__ __launch_bounds__(512, 4) void k_all(
    const float* __restrict__ scores, const float* __restrict__ veh,
    const float* __restrict__ cust, const float* __restrict__ edge,
    const float* __restrict__ ew1, const float* __restrict__ eb1,
    const float* __restrict__ ew2, const float* __restrict__ eb2,
    const float* __restrict__ sw1, const float* __restrict__ sb1,
    const float* __restrict__ sw2, const float* __restrict__ sb2,
    const float* __restrict__ cand_w, const float* __restrict__ cand_b,
    const float* __restrict__ edge_w, const float* __restrict__ gbp,
    float* __restrict__ out)
{
    __shared__ float4 red[512];
    __shared__ float sin_[2 * DD];
    __shared__ float hg[GG];
    __shared__ float slds[KK];

    const int n = blockIdx.x;
    const int t = threadIdx.x;
    const int lane = t & 63;
    const int r = lane & 31;

    const int ko = r & 3;        // owned gate/expert channel
    const int jg = r >> 2;       // owned hidden quad (0..7)
    const bool kb0 = (r & 1) != 0;
    const bool kb1 = (r & 2) != 0;

    // per-lane constant weights (latency hidden behind Phase A streaming)
    const float4* ew4 = (const float4*)edge_w;            // (D,K)
    const float4 wqa = ew4[4 * r + 0];
    const float4 wqb = ew4[4 * r + 1];
    const float4 wqc = ew4[4 * r + 2];
    const float4 wqd = ew4[4 * r + 3];
    const float cw0 = cand_w[0 * KK + ko];
    const float cw1 = cand_w[1 * KK + ko];
    const float cw2 = cand_w[2 * KK + ko];
    const float cb  = cand_b[ko];
    const float4* w1f = (const float4*)ew1;               // (K,S,H)
    const float4 w1a = w1f[(ko * SS + 0) * (HH / 4) + jg];
    const float4 w1b = w1f[(ko * SS + 1) * (HH / 4) + jg];
    const float4 w1c = w1f[(ko * SS + 2) * (HH / 4) + jg];
    const float4 b1v = ((const float4*)eb1)[ko * (HH / 4) + jg];
    const float4 w2v = ((const float4*)ew2)[ko * (HH / 4) + jg];
    const float b2o8 = 0.125f * eb2[ko];   // b2 folded into per-lane partial
    const float gbv = gbp[0];
    const float alpha = 1.0f / (1.0f + __expf(-gbv));
    const float onema = 1.0f - alpha;

    // ---- Phase A: mean over L of cust[n] ----
    const int c = t & 31;
    const int rs = t >> 5;
    const float4* cp = (const float4*)(cust + (size_t)n * LL * DD);
    float4 a0 = make_float4(0.f, 0.f, 0.f, 0.f), a1 = a0, a2 = a0, a3 = a0;
    #pragma unroll 4
    for (int i = 0; i < 16; ++i) {
        float4 v0 = cp[(rs + 16 * i      ) * 32 + c];
        float4 v1 = cp[(rs + 16 * i + 256) * 32 + c];
        float4 v2 = cp[(rs + 16 * i + 512) * 32 + c];
        float4 v3 = cp[(rs + 16 * i + 768) * 32 + c];
        a0.x += v0.x; a0.y += v0.y; a0.z += v0.z; a0.w += v0.w;
        a1.x += v1.x; a1.y += v1.y; a1.z += v1.z; a1.w += v1.w;
        a2.x += v2.x; a2.y += v2.y; a2.z += v2.z; a2.w += v2.w;
        a3.x += v3.x; a3.y += v3.y; a3.z += v3.z; a3.w += v3.w;
    }
    a0.x += a1.x + a2.x + a3.x;
    a0.y += a1.y + a2.y + a3.y;
    a0.z += a1.z + a2.z + a3.z;
    a0.w += a1.w + a2.w + a3.w;
    red[t] = a0;
    __syncthreads();

    if (t < 32) {
        float4 s = red[t];
        #pragma unroll
        for (int i = 1; i < 16; i++) {
            float4 v = red[i * 32 + t];
            s.x += v.x; s.y += v.y; s.z += v.z; s.w += v.w;
        }
        const float inv = 1.0f / (float)LL;
        sin_[DD + 4 * t + 0] = s.x * inv;
        sin_[DD + 4 * t + 1] = s.y * inv;
        sin_[DD + 4 * t + 2] = s.z * inv;
        sin_[DD + 4 * t + 3] = s.w * inv;
        float4 vv = ((const float4*)(veh + (size_t)n * DD))[t];
        sin_[4 * t + 0] = vv.x; sin_[4 * t + 1] = vv.y;
        sin_[4 * t + 2] = vv.z; sin_[4 * t + 3] = vv.w;
    }
    __syncthreads();

    // ---- Phase B: situation MLP ----
    if (t < GG) {
        float a = sb1[t];
        #pragma unroll 8
        for (int i = 0; i < 2 * DD; i++)
            a = fmaf(sin_[i], sw1[i * GG + t], a);
        hg[t] = fast_gelu(a);
    }
    __syncthreads();
    if (t < KK) {
        float a = sb2[t];
        #pragma unroll
        for (int g = 0; g < GG; g++)
            a = fmaf(hg[g], sw2[g * KK + t], a);
        slds[t] = a;
    }
    __syncthreads();

    // hoisted per-n sit-logit select + alpha blend
    const float sl0 = slds[0], sl1 = slds[1], sl2 = slds[2], sl3 = slds[3];
    float sa_ = kb0 ? sl1 : sl0;
    float sb_ = kb0 ? sl3 : sl2;
    float so  = kb1 ? sb_ : sa_;
    const float sbase = fmaf(alpha, so, onema * cb);

    // ---- Phase C: 1024 elements, 4 chains in flight ----
    const int base_el = t >> 5;   // 0..15
    const float* sc_base = scores + (size_t)n * LL * SS;
    const float* ed_base = edge + (size_t)n * LL * DD;
    float* out_base = out + (size_t)n * LL;

    for (int i = 0; i < 16; ++i) {
        const int e0 = base_el + i * 64;
        float4 ev[4];
        float s0[4], s1[4], s2[4];
        #pragma unroll
        for (int u = 0; u < 4; ++u)
            ev[u] = *(const float4*)(ed_base + (size_t)(e0 + u * 16) * DD + r * 4);
        #pragma unroll
        for (int u = 0; u < 4; ++u) {
            const int el = e0 + u * 16;
            s0[u] = sc_base[el * 3 + 0];
            s1[u] = sc_base[el * 3 + 1];
            s2[u] = sc_base[el * 3 + 2];
        }

        // edge-dot partials for all 4 k over the 4 owned dims
        float p0[4], p1[4], p2[4], p3[4];
        #pragma unroll
        for (int u = 0; u < 4; ++u) {
            p0[u] = fmaf(ev[u].x, wqa.x, fmaf(ev[u].y, wqb.x, fmaf(ev[u].z, wqc.x, ev[u].w * wqd.x)));
            p1[u] = fmaf(ev[u].x, wqa.y, fmaf(ev[u].y, wqb.y, fmaf(ev[u].z, wqc.y, ev[u].w * wqd.y)));
            p2[u] = fmaf(ev[u].x, wqa.z, fmaf(ev[u].y, wqb.z, fmaf(ev[u].z, wqc.z, ev[u].w * wqd.z)));
            p3[u] = fmaf(ev[u].x, wqa.w, fmaf(ev[u].y, wqb.w, fmaf(ev[u].z, wqc.w, ev[u].w * wqd.w)));
        }
        // butterfly exchange: stage xor1 (2 swz), stage xor2 (1 swz)
        float P0[4], P2[4];
        #pragma unroll
        for (int u = 0; u < 4; ++u) {
            float g0 = kb0 ? p0[u] : p1[u];
            float g2 = kb0 ? p2[u] : p3[u];
            float k0 = kb0 ? p1[u] : p0[u];
            float k2 = kb0 ? p3[u] : p2[u];
            P0[u] = k0 + swz<SWZ1>(g0);
            P2[u] = k2 + swz<SWZ1>(g2);
        }
        float q[4];
        #pragma unroll
        for (int u = 0; u < 4; ++u) {
            float gv = kb1 ? P0[u] : P2[u];
            float kv = kb1 ? P2[u] : P0[u];
            q[u] = kv + swz<SWZ2>(gv);
        }
        #pragma unroll
        for (int u = 0; u < 4; ++u) q[u] += swz<SWZ4>(q[u]);
        #pragma unroll
        for (int u = 0; u < 4; ++u) q[u] += swz<SWZ8>(q[u]);
        #pragma unroll
        for (int u = 0; u < 4; ++u) q[u] += swz<SWZ16>(q[u]);
        // q[u] = edge_dot[k=ko], replicated over the 8 lanes sharing ko

        // gate logit -> exp (no max-sub: |gl| ~ 3, fp32 exp is exact enough)
        float ex[4];
        #pragma unroll
        for (int u = 0; u < 4; ++u) {
            float sdot = fmaf(s0[u], cw0, fmaf(s1[u], cw1, s2[u] * cw2));
            float gl = fmaf(onema, sdot + q[u], sbase);
            ex[u] = __expf(gl);
        }
        float se[4];
        #pragma unroll
        for (int u = 0; u < 4; ++u) se[u] = ex[u] + swz<SWZ1>(ex[u]);
        #pragma unroll
        for (int u = 0; u < 4; ++u) se[u] += swz<SWZ2>(se[u]);

        // expert MLP: 4 hidden units of own k; fold gate weight + bias
        float tk[4];
        #pragma unroll
        for (int u = 0; u < 4; ++u) {
            float gw = ex[u] * __builtin_amdgcn_rcpf(se[u]);
            float z, h, acc;
            z = fmaf(s0[u], w1a.x, fmaf(s1[u], w1b.x, fmaf(s2[u], w1c.x, b1v.x))); h = fast_gelu(z); acc = h * w2v.x;
            z = fmaf(s0[u], w1a.y, fmaf(s1[u], w1b.y, fmaf(s2[u], w1c.y, b1v.y))); h = fast_gelu(z); acc = fmaf(h, w2v.y, acc);
            z = fmaf(s0[u], w1a.z, fmaf(s1[u], w1b.z, fmaf(s2[u], w1c.z, b1v.z))); h = fast_gelu(z); acc = fmaf(h, w2v.z, acc);
            z = fmaf(s0[u], w1a.w, fmaf(s1[u], w1b.w, fmaf(s2[u], w1c.w, b1v.w))); h = fast_gelu(z); acc = fmaf(h, w2v.w, acc);
            tk[u] = gw * (acc + b2o8);
        }
        // single full 32-lane reduce = sum over h-groups AND over k
        #pragma unroll
        for (int u = 0; u < 4; ++u) tk[u] += swz<SWZ1>(tk[u]);
        #pragma unroll
        for (int u = 0; u < 4; ++u) tk[u] += swz<SWZ2>(tk[u]);
        #pragma unroll
        for (int u = 0; u < 4; ++u) tk[u] += swz<SWZ4>(tk[u]);
        #pragma unroll
        for (int u = 0; u < 4; ++u) tk[u] += swz<SWZ8>(tk[u]);
        #pragma unroll
        for (int u = 0; u < 4; ++u) tk[u] += swz<SWZ16>(tk[u]);

        if (r == 0) {
            #pragma unroll
            for (int u = 0; u < 4; ++u)
                out_base[e0 + u * 16] = tk[u];
        }
    }
}

extern "C" void kernel_launch(void* const* d_in, const int* in_sizes, int n_in,
                              void* d_out, int out_size, void* d_ws, size_t ws_size,
                              hipStream_t stream)
{
    const float* scores = (const float*)d_in[0];
    const float* veh    = (const float*)d_in[1];
    const float* cust   = (const float*)d_in[2];
    const float* edge   = (const float*)d_in[3];
    const float* ew1    = (const float*)d_in[4];
    const float* eb1    = (const float*)d_in[5];
    const float* ew2    = (const float*)d_in[6];
    const float* eb2    = (const float*)d_in[7];
    const float* sw1    = (const float*)d_in[8];
    const float* sb1    = (const float*)d_in[9];
    const float* sw2    = (const float*)d_in[10];
    const float* sb2    = (const float*)d_in[11];
    const float* cw     = (const float*)d_in[12];
    const float* cb     = (const float*)d_in[13];
    const float* egw    = (const float*)d_in[14];
    const float* gb     = (const float*)d_in[15];
    float* out = (float*)d_out;

    hipLaunchKernelGGL(k_all, dim3(NN), dim3(512), 0, stream,
                       scores, veh, cust, edge, ew1, eb1, ew2, eb2,
                       sw1, sb1, sw2, sb2, cw, cb, egw, gb, out);
}